// Round 16
// baseline (616.677 us; speedup 1.0000x reference)
//
#include <hip/hip_runtime.h>
#include <hip/hip_bf16.h>
#include <hip/hip_cooperative_groups.h>
#include <stdint.h>

namespace cg = cooperative_groups;

#define NN 8192
#define DD 256
#define EE 131072
#define KK 1024   // 4*DD
#define BKT 32    // K per LDS tile
#define NT 32     // KK/BKT
#define CAP 128   // edge bucket capacity per node

typedef __attribute__((ext_vector_type(8))) short short8;
typedef __attribute__((ext_vector_type(4))) float f32x4;

#define S1 0.35355339059327373f   // sqrt(1/8)
#define S3 0.6123724356957945f    // sqrt(3/8)

__device__ inline short f2bf(float x) {
  __hip_bfloat16 b = __float2bfloat16(x);
  union { __hip_bfloat16 b; short s; } u; u.b = b; return u.s;
}
__device__ inline float bf2f(short x) {
  union { unsigned u; float f; } c; c.u = ((unsigned)(unsigned short)x) << 16; return c.f;
}
__device__ inline void async_load16(const void* g, void* l) {
  __builtin_amdgcn_global_load_lds((const __attribute__((address_space(1))) void*)g,
                                   (__attribute__((address_space(3))) void*)l, 16, 0, 0);
}

// ---------------- fused chain: clear + scatter + spmm1..3 (cooperative) ----------------
// 5 graph nodes -> 1. Phases separated by grid.sync() (device-scope fences +
// cross-XCD visibility handled by cooperative groups). 1024 blocks x 256
// threads = 4 blocks/CU; wave-stride: 4096 waves cover 8192 nodes (2/wave).
__global__ __launch_bounds__(256, 4) void chain_k(
    const float* __restrict__ h, const float* __restrict__ e,
    const int* __restrict__ src, const int* __restrict__ dst,
    int* __restrict__ cursor, int2* __restrict__ edges,
    float* __restrict__ k1, short* __restrict__ xbb, short* __restrict__ xcb,
    short* __restrict__ Y) {
  cg::grid_group grid = cg::this_grid();
  int tid = blockIdx.x * 256 + threadIdx.x;   // 0..262143
  int nthreads = gridDim.x * 256;
  int lane = tid & 63;
  int gw = tid >> 6;            // global wave id
  int nw = nthreads >> 6;       // wave count (4096)

  // phase 0: clear cursors
  if (tid < NN) cursor[tid] = 0;
  grid.sync();

  // phase 1: scatter edges into per-node buckets
  for (int i = tid; i < EE; i += nthreads) {
    int d = dst[i], s = src[i];
    int pos = atomicAdd(&cursor[d], 1);
    if (pos < CAP) {
      float w = (s == d) ? -1.0f : e[i];
      union { float f; int i; } wb; wb.f = w;
      edges[d * CAP + pos] = make_int2(s, wb.i);
    }
  }
  grid.sync();

  // phase 2: spmm1 — k1=spmm(h); xb=h+k1/3; Y0=bf16(S1*h); Yb=bf16(S3*xb)
  for (int v = gw; v < NN; v += nw) {
    int cnt = min(cursor[v], CAP);
    const int2* ev = &edges[v * CAP];
    float ax = 0.f, ay = 0.f, az = 0.f, aw = 0.f;
    for (int j = 0; j < cnt; ++j) {
      int2 ed = ev[j];
      union { int i; float f; } wb; wb.i = ed.y; float w = wb.f;
      float4 xv = *reinterpret_cast<const float4*>(&h[ed.x * DD + lane * 4]);
      ax += w * xv.x; ay += w * xv.y; az += w * xv.z; aw += w * xv.w;
    }
    int idx = v * DD + lane * 4;
    float4 hv = *reinterpret_cast<const float4*>(&h[idx]);
    float4 k; k.x = ax; k.y = ay; k.z = az; k.w = aw;
    *reinterpret_cast<float4*>(&k1[idx]) = k;
    float bx = hv.x + ax * (1.f / 3.f), by = hv.y + ay * (1.f / 3.f);
    float bz = hv.z + az * (1.f / 3.f), bw = hv.w + aw * (1.f / 3.f);
    short4 xb4; xb4.x = f2bf(bx); xb4.y = f2bf(by); xb4.z = f2bf(bz); xb4.w = f2bf(bw);
    *reinterpret_cast<short4*>(&xbb[idx]) = xb4;
    short4 y0; y0.x = f2bf(S1 * hv.x); y0.y = f2bf(S1 * hv.y);
    y0.z = f2bf(S1 * hv.z); y0.w = f2bf(S1 * hv.w);
    *reinterpret_cast<short4*>(&Y[(size_t)v * KK + lane * 4]) = y0;
    short4 yb; yb.x = f2bf(S3 * bx); yb.y = f2bf(S3 * by);
    yb.z = f2bf(S3 * bz); yb.w = f2bf(S3 * bw);
    *reinterpret_cast<short4*>(&Y[(size_t)v * KK + DD + lane * 4]) = yb;
  }
  grid.sync();

  // phase 3: spmm2 — k2=spmm(xb); xc=h+k2-k1/3; Yc=bf16(S3*xc)
  for (int v = gw; v < NN; v += nw) {
    int cnt = min(cursor[v], CAP);
    const int2* ev = &edges[v * CAP];
    float ax = 0.f, ay = 0.f, az = 0.f, aw = 0.f;
    for (int j = 0; j < cnt; ++j) {
      int2 ed = ev[j];
      union { int i; float f; } wb; wb.i = ed.y; float w = wb.f;
      short4 xv = *reinterpret_cast<const short4*>(&xbb[ed.x * DD + lane * 4]);
      ax += w * bf2f(xv.x); ay += w * bf2f(xv.y); az += w * bf2f(xv.z); aw += w * bf2f(xv.w);
    }
    int idx = v * DD + lane * 4;
    float4 hv = *reinterpret_cast<const float4*>(&h[idx]);
    float4 k1v = *reinterpret_cast<const float4*>(&k1[idx]);
    float cx = hv.x + ax - k1v.x * (1.f / 3.f), cy = hv.y + ay - k1v.y * (1.f / 3.f);
    float cz = hv.z + az - k1v.z * (1.f / 3.f), cw = hv.w + aw - k1v.w * (1.f / 3.f);
    short4 xc4; xc4.x = f2bf(cx); xc4.y = f2bf(cy); xc4.z = f2bf(cz); xc4.w = f2bf(cw);
    *reinterpret_cast<short4*>(&xcb[idx]) = xc4;
    short4 yc; yc.x = f2bf(S3 * cx); yc.y = f2bf(S3 * cy);
    yc.z = f2bf(S3 * cz); yc.w = f2bf(S3 * cw);
    *reinterpret_cast<short4*>(&Y[(size_t)v * KK + 2 * DD + lane * 4]) = yc;
  }
  grid.sync();

  // phase 4: spmm3 — k3=spmm(xc); xd=2h+(2/3)k1-xc+k3; Yd=bf16(S1*xd)
  for (int v = gw; v < NN; v += nw) {
    int cnt = min(cursor[v], CAP);
    const int2* ev = &edges[v * CAP];
    float ax = 0.f, ay = 0.f, az = 0.f, aw = 0.f;
    for (int j = 0; j < cnt; ++j) {
      int2 ed = ev[j];
      union { int i; float f; } wb; wb.i = ed.y; float w = wb.f;
      short4 xv = *reinterpret_cast<const short4*>(&xcb[ed.x * DD + lane * 4]);
      ax += w * bf2f(xv.x); ay += w * bf2f(xv.y); az += w * bf2f(xv.z); aw += w * bf2f(xv.w);
    }
    int idx = v * DD + lane * 4;
    float4 hv = *reinterpret_cast<const float4*>(&h[idx]);
    float4 k1v = *reinterpret_cast<const float4*>(&k1[idx]);
    short4 xc4 = *reinterpret_cast<const short4*>(&xcb[idx]);
    float dx = 2.f * hv.x + (2.f / 3.f) * k1v.x - bf2f(xc4.x) + ax;
    float dy = 2.f * hv.y + (2.f / 3.f) * k1v.y - bf2f(xc4.y) + ay;
    float dz = 2.f * hv.z + (2.f / 3.f) * k1v.z - bf2f(xc4.z) + az;
    float dw = 2.f * hv.w + (2.f / 3.f) * k1v.w - bf2f(xc4.w) + aw;
    short4 yd; yd.x = f2bf(S1 * dx); yd.y = f2bf(S1 * dy);
    yd.z = f2bf(S1 * dz); yd.w = f2bf(S1 * dw);
    *reinterpret_cast<short4*>(&Y[(size_t)v * KK + 3 * DD + lane * 4]) = yd;
  }
}

// ---------------- symmetric Gram GEMM: C = Y * Y^T ----------------
// R15 version (best, 178.6us): 256x128 tile, 3 rotating buffers, counted
// vmcnt(6), 2 blocks/CU, LDS-transposed 256-B float4 nt stores.
__global__ __launch_bounds__(256, 2) void gram_gemm(const short* __restrict__ Y,
                                                    float* __restrict__ C) {
  __shared__ __attribute__((aligned(16))) short lds[36864];   // 72 KiB: 3 x 24 KiB

  int logical = (blockIdx.x & 7) * 132 + (blockIdx.x >> 3);   // XCD swizzle, 1056 = 8*132
  int brow = 0, rem = logical;
  while (rem >= 64 - 2 * brow) { rem -= 64 - 2 * brow; ++brow; }
  int bcol = 2 * brow + rem;

  int t = threadIdx.x;
  int lane = t & 63, wv = t >> 6;
  int wr = wv >> 1, wc = wv & 1;   // 2 x 2 wave grid; per-wave C: 128x64
  int l15 = lane & 15;
  int ksel = ((lane >> 4) ^ ((lane >> 1) & 3)) * 8;

  int srow = t >> 2;                   // 0..63
  int scol = ((t & 3) ^ ((t >> 3) & 3)) * 8;
  const short* gA[4];
#pragma unroll
  for (int j = 0; j < 4; j++)
    gA[j] = Y + (size_t)(brow * 256 + j * 64 + srow) * KK + scol;
  const short* gB[2];
#pragma unroll
  for (int j = 0; j < 2; j++)
    gB[j] = Y + (size_t)(bcol * 128 + j * 64 + srow) * KK + scol;

  f32x4 acc[8][4] = {};

#define STAGE(tt, b) do {                                                   \
    short* base_ = lds + (b) * 12288;                                       \
    async_load16(gA[0] + (size_t)(tt) * BKT, base_ + 0 * 2048 + wv * 512);  \
    async_load16(gA[1] + (size_t)(tt) * BKT, base_ + 1 * 2048 + wv * 512);  \
    async_load16(gA[2] + (size_t)(tt) * BKT, base_ + 2 * 2048 + wv * 512);  \
    async_load16(gA[3] + (size_t)(tt) * BKT, base_ + 3 * 2048 + wv * 512);  \
    async_load16(gB[0] + (size_t)(tt) * BKT, base_ + 8192 + wv * 512);      \
    async_load16(gB[1] + (size_t)(tt) * BKT, base_ + 10240 + wv * 512);     \
  } while (0)

  STAGE(0, 0);
  STAGE(1, 1);

  for (int tt = 0; tt < NT; ++tt) {
    if (tt < NT - 1) asm volatile("s_waitcnt vmcnt(6)" ::: "memory");
    else             asm volatile("s_waitcnt vmcnt(0)" ::: "memory");
    __builtin_amdgcn_s_barrier();
    __builtin_amdgcn_sched_barrier(0);
    if (tt + 2 < NT) {
      int b = tt + 2;
      STAGE(b, b % 3);
    }

    const short* bufp = lds + (tt % 3) * 12288;
    short8 a[8], b[4];
#pragma unroll
    for (int m = 0; m < 8; m++)
      a[m] = *reinterpret_cast<const short8*>(
          &bufp[(wr * 128 + m * 16 + l15) * 32 + ksel]);
#pragma unroll
    for (int n = 0; n < 4; n++)
      b[n] = *reinterpret_cast<const short8*>(
          &bufp[8192 + (wc * 64 + n * 16 + l15) * 32 + ksel]);
    __builtin_amdgcn_s_setprio(1);
#pragma unroll
    for (int m = 0; m < 8; m++)
#pragma unroll
      for (int n = 0; n < 4; n++)
        acc[m][n] = __builtin_amdgcn_mfma_f32_16x16x32_bf16(a[m], b[n], acc[m][n], 0, 0, 0);
    __builtin_amdgcn_s_setprio(0);
  }

  // ---- epilogue: LDS-transposed, 256-B contiguous float4 segments, all nt ----
  int rbase = (lane >> 4) * 4;
  int row0 = brow * 256 + wr * 128;
  int colb = bcol * 128 + wc * 64;

  float* tbw = reinterpret_cast<float*>(lds) + wv * 2112;
  __builtin_amdgcn_s_barrier();
  __builtin_amdgcn_sched_barrier(0);

#pragma unroll
  for (int m = 0; m < 8; m++) {
#pragma unroll
    for (int n = 0; n < 4; n++)
#pragma unroll
      for (int r = 0; r < 4; r++)
        tbw[(rbase + r) * 68 + n * 16 + l15] = acc[m][n][r];
#pragma unroll
    for (int dr = 0; dr < 4; dr++) {
      f32x4 vv = *reinterpret_cast<const f32x4*>(
          &tbw[(dr * 4 + (lane >> 4)) * 68 + l15 * 4]);
      __builtin_nontemporal_store(
          vv, reinterpret_cast<f32x4*>(
              &C[(size_t)(row0 + m * 16 + dr * 4 + (lane >> 4)) * NN + colb + l15 * 4]));
    }
  }

#pragma unroll
  for (int n = 0; n < 4; n++) {
#pragma unroll
    for (int m = 0; m < 8; m++)
#pragma unroll
      for (int r = 0; r < 4; r++)
        tbw[l15 * 132 + m * 16 + rbase + r] = acc[m][n][r];
#pragma unroll
    for (int dr = 0; dr < 4; dr++)
#pragma unroll
      for (int half = 0; half < 2; half++) {
        f32x4 vv = *reinterpret_cast<const f32x4*>(
            &tbw[(dr * 4 + (lane >> 4)) * 132 + half * 64 + l15 * 4]);
        __builtin_nontemporal_store(
            vv, reinterpret_cast<f32x4*>(
                &C[(size_t)(colb + n * 16 + dr * 4 + (lane >> 4)) * NN +
                   row0 + half * 64 + l15 * 4]));
      }
  }
#undef STAGE
}

// ---------------- launch ----------------

extern "C" void kernel_launch(void* const* d_in, const int* in_sizes, int n_in,
                              void* d_out, int out_size, void* d_ws, size_t ws_size,
                              hipStream_t stream) {
  const float* h = (const float*)d_in[0];
  const float* e = (const float*)d_in[1];
  const int* src = (const int*)d_in[2];
  const int* dst = (const int*)d_in[3];
  float* out = (float*)d_out;
  char* ws = (char*)d_ws;

  short* Y     = (short*)(ws);                    // 16 MB
  short* xbb   = (short*)(ws + 20971520);         // 4 MB
  short* xcb   = (short*)(ws + 25165824);         // 4 MB
  float* k1    = (float*)(ws + 29360128);         // 8 MB
  int* cursor  = (int*)(ws + 37748736);           // 32 KB
  int2* edges  = (int2*)(ws + 37781504);          // 8 MB (8192 * 128 * 8B)

  void* args[] = {(void*)&h, (void*)&e, (void*)&src, (void*)&dst,
                  (void*)&cursor, (void*)&edges, (void*)&k1,
                  (void*)&xbb, (void*)&xcb, (void*)&Y};
  hipLaunchCooperativeKernel(reinterpret_cast<void*>(chain_k),
                             dim3(1024), dim3(256), args, 0, stream);

  gram_gemm<<<1056, 256, 0, stream>>>(Y, out);
}

// Round 17
// 159.959 us; speedup vs baseline: 3.8552x; 3.8552x over previous
//
#include <hip/hip_runtime.h>
#include <hip/hip_bf16.h>
#include <stdint.h>

#define NN 8192
#define DD 256
#define EE 131072
#define KK 1024   // 4*DD
#define BKT 32    // K per LDS tile
#define NT 32     // KK/BKT
#define CAP 128   // edge bucket capacity per node

typedef __attribute__((ext_vector_type(8))) short short8;
typedef __attribute__((ext_vector_type(4))) float f32x4;

#define S1 0.35355339059327373f   // sqrt(1/8)
#define S3 0.6123724356957945f    // sqrt(3/8)

__device__ inline short f2bf(float x) {
  __hip_bfloat16 b = __float2bfloat16(x);
  union { __hip_bfloat16 b; short s; } u; u.b = b; return u.s;
}
__device__ inline float bf2f(short x) {
  union { unsigned u; float f; } c; c.u = ((unsigned)(unsigned short)x) << 16; return c.f;
}
__device__ inline void async_load16(const void* g, void* l) {
  __builtin_amdgcn_global_load_lds((const __attribute__((address_space(1))) void*)g,
                                   (__attribute__((address_space(3))) void*)l, 16, 0, 0);
}

// ---------------- cursor clear ----------------
__global__ void clear_k(int* __restrict__ cursor) {
  cursor[blockIdx.x * 256 + threadIdx.x] = 0;
}

// ---------------- bucketed edge build (no scan) ----------------
__global__ void scatter_edges(const int* __restrict__ src, const int* __restrict__ dst,
                              const float* __restrict__ e, int* __restrict__ cursor,
                              int2* __restrict__ edges) {
  int i = blockIdx.x * 256 + threadIdx.x;
  if (i >= EE) return;
  int d = dst[i], s = src[i];
  int pos = atomicAdd(&cursor[d], 1);
  if (pos < CAP) {
    float w = (s == d) ? -1.0f : e[i];
    union { float f; int i; } wb; wb.f = w;
    edges[d * CAP + pos] = make_int2(s, wb.i);
  }
}

// ---------------- SpMM stages (one wave per node, pipelined gathers) ----------------
// Edge list preloaded coalesced (ev[lane], one 8-B load for 64 edges) and
// distributed via __shfl; x4 manual unroll with 2 accumulator sets keeps 4
// gather loads in flight (R16 probe: serial per-edge chain was the chain's
// latency bottleneck — load ev[j] -> addr -> gather -> fmac, ~500 cyc/edge).
#define GATHER_ACCUM(LOADX)                                                  \
  float ax = 0.f, ay = 0.f, az = 0.f, aw = 0.f;                              \
  float bx2 = 0.f, by2 = 0.f, bz2 = 0.f, bw2 = 0.f;                          \
  {                                                                          \
    int2 eh = ev[lane];   /* coalesced preload of first 64 edges */          \
    int n64 = min(cnt, 64);                                                  \
    int j = 0;                                                               \
    for (; j + 4 <= n64; j += 4) {                                           \
      int s0 = __shfl(eh.x, j),     s1 = __shfl(eh.x, j + 1);                \
      int s2 = __shfl(eh.x, j + 2), s3 = __shfl(eh.x, j + 3);                \
      float w0 = __int_as_float(__shfl(eh.y, j));                            \
      float w1 = __int_as_float(__shfl(eh.y, j + 1));                        \
      float w2 = __int_as_float(__shfl(eh.y, j + 2));                        \
      float w3 = __int_as_float(__shfl(eh.y, j + 3));                        \
      float4 x0 = LOADX(s0); float4 x1 = LOADX(s1);                          \
      float4 x2 = LOADX(s2); float4 x3 = LOADX(s3);                          \
      ax  += w0 * x0.x; ay  += w0 * x0.y; az  += w0 * x0.z; aw  += w0 * x0.w;\
      bx2 += w1 * x1.x; by2 += w1 * x1.y; bz2 += w1 * x1.z; bw2 += w1 * x1.w;\
      ax  += w2 * x2.x; ay  += w2 * x2.y; az  += w2 * x2.z; aw  += w2 * x2.w;\
      bx2 += w3 * x3.x; by2 += w3 * x3.y; bz2 += w3 * x3.z; bw2 += w3 * x3.w;\
    }                                                                        \
    for (; j < n64; ++j) {                                                   \
      int s0 = __shfl(eh.x, j);                                              \
      float w0 = __int_as_float(__shfl(eh.y, j));                            \
      float4 x0 = LOADX(s0);                                                 \
      ax += w0 * x0.x; ay += w0 * x0.y; az += w0 * x0.z; aw += w0 * x0.w;    \
    }                                                                        \
    for (int jj = 64; jj < cnt; ++jj) {   /* rare tail, cnt > 64 */          \
      int2 ed = ev[jj];                                                      \
      float w0 = __int_as_float(ed.y);                                       \
      float4 x0 = LOADX(ed.x);                                               \
      ax += w0 * x0.x; ay += w0 * x0.y; az += w0 * x0.z; aw += w0 * x0.w;    \
    }                                                                        \
    ax += bx2; ay += by2; az += bz2; aw += bw2;                              \
  }

__global__ void spmm1_k(const float* __restrict__ h, const int* __restrict__ cursor,
                        const int2* __restrict__ edges, float* __restrict__ k1,
                        short* __restrict__ xbb, short* __restrict__ Y) {
  int tid = blockIdx.x * 256 + threadIdx.x;
  int v = tid >> 6, lane = tid & 63;
  int cnt = min(cursor[v], CAP);
  const int2* ev = &edges[v * CAP];
#define LOADF4(s) (*reinterpret_cast<const float4*>(&h[(s) * DD + lane * 4]))
  GATHER_ACCUM(LOADF4)
#undef LOADF4
  int idx = v * DD + lane * 4;
  float4 hv = *reinterpret_cast<const float4*>(&h[idx]);
  float4 k; k.x = ax; k.y = ay; k.z = az; k.w = aw;
  *reinterpret_cast<float4*>(&k1[idx]) = k;
  float bx = hv.x + ax * (1.f / 3.f), by = hv.y + ay * (1.f / 3.f);
  float bz = hv.z + az * (1.f / 3.f), bw = hv.w + aw * (1.f / 3.f);
  short4 xb4; xb4.x = f2bf(bx); xb4.y = f2bf(by); xb4.z = f2bf(bz); xb4.w = f2bf(bw);
  *reinterpret_cast<short4*>(&xbb[idx]) = xb4;
  short4 y0; y0.x = f2bf(S1 * hv.x); y0.y = f2bf(S1 * hv.y);
  y0.z = f2bf(S1 * hv.z); y0.w = f2bf(S1 * hv.w);
  *reinterpret_cast<short4*>(&Y[(size_t)v * KK + lane * 4]) = y0;
  short4 yb; yb.x = f2bf(S3 * bx); yb.y = f2bf(S3 * by);
  yb.z = f2bf(S3 * bz); yb.w = f2bf(S3 * bw);
  *reinterpret_cast<short4*>(&Y[(size_t)v * KK + DD + lane * 4]) = yb;
}

__device__ inline float4 ld_bf4(const short* p, int s, int lane) {
  short4 xv = *reinterpret_cast<const short4*>(&p[s * DD + lane * 4]);
  float4 r; r.x = bf2f(xv.x); r.y = bf2f(xv.y); r.z = bf2f(xv.z); r.w = bf2f(xv.w);
  return r;
}

__global__ void spmm2_k(const short* __restrict__ xbb, const float* __restrict__ h,
                        const float* __restrict__ k1, const int* __restrict__ cursor,
                        const int2* __restrict__ edges, short* __restrict__ xcb,
                        short* __restrict__ Y) {
  int tid = blockIdx.x * 256 + threadIdx.x;
  int v = tid >> 6, lane = tid & 63;
  int cnt = min(cursor[v], CAP);
  const int2* ev = &edges[v * CAP];
#define LOADB4(s) ld_bf4(xbb, (s), lane)
  GATHER_ACCUM(LOADB4)
#undef LOADB4
  int idx = v * DD + lane * 4;
  float4 hv = *reinterpret_cast<const float4*>(&h[idx]);
  float4 k1v = *reinterpret_cast<const float4*>(&k1[idx]);
  float cx = hv.x + ax - k1v.x * (1.f / 3.f), cy = hv.y + ay - k1v.y * (1.f / 3.f);
  float cz = hv.z + az - k1v.z * (1.f / 3.f), cw = hv.w + aw - k1v.w * (1.f / 3.f);
  short4 xc4; xc4.x = f2bf(cx); xc4.y = f2bf(cy); xc4.z = f2bf(cz); xc4.w = f2bf(cw);
  *reinterpret_cast<short4*>(&xcb[idx]) = xc4;
  short4 yc; yc.x = f2bf(S3 * cx); yc.y = f2bf(S3 * cy);
  yc.z = f2bf(S3 * cz); yc.w = f2bf(S3 * cw);
  *reinterpret_cast<short4*>(&Y[(size_t)v * KK + 2 * DD + lane * 4]) = yc;
}

__global__ void spmm3_k(const short* __restrict__ xcb, const float* __restrict__ h,
                        const float* __restrict__ k1, const int* __restrict__ cursor,
                        const int2* __restrict__ edges, short* __restrict__ Y) {
  int tid = blockIdx.x * 256 + threadIdx.x;
  int v = tid >> 6, lane = tid & 63;
  int cnt = min(cursor[v], CAP);
  const int2* ev = &edges[v * CAP];
#define LOADC4(s) ld_bf4(xcb, (s), lane)
  GATHER_ACCUM(LOADC4)
#undef LOADC4
  int idx = v * DD + lane * 4;
  float4 hv = *reinterpret_cast<const float4*>(&h[idx]);
  float4 k1v = *reinterpret_cast<const float4*>(&k1[idx]);
  short4 xc4 = *reinterpret_cast<const short4*>(&xcb[idx]);
  float dx = 2.f * hv.x + (2.f / 3.f) * k1v.x - bf2f(xc4.x) + ax;
  float dy = 2.f * hv.y + (2.f / 3.f) * k1v.y - bf2f(xc4.y) + ay;
  float dz = 2.f * hv.z + (2.f / 3.f) * k1v.z - bf2f(xc4.z) + az;
  float dw = 2.f * hv.w + (2.f / 3.f) * k1v.w - bf2f(xc4.w) + aw;
  short4 yd; yd.x = f2bf(S1 * dx); yd.y = f2bf(S1 * dy);
  yd.z = f2bf(S1 * dz); yd.w = f2bf(S1 * dw);
  *reinterpret_cast<short4*>(&Y[(size_t)v * KK + 3 * DD + lane * 4]) = yd;
}

// ---------------- symmetric Gram GEMM: C = Y * Y^T ----------------
// R15 version (best, 178.6us): 256x128 tile, 3 rotating buffers, counted
// vmcnt(6), 2 blocks/CU, LDS-transposed 256-B float4 nt stores.
__global__ __launch_bounds__(256, 2) void gram_gemm(const short* __restrict__ Y,
                                                    float* __restrict__ C) {
  __shared__ __attribute__((aligned(16))) short lds[36864];   // 72 KiB: 3 x 24 KiB

  int logical = (blockIdx.x & 7) * 132 + (blockIdx.x >> 3);   // XCD swizzle, 1056 = 8*132
  int brow = 0, rem = logical;
  while (rem >= 64 - 2 * brow) { rem -= 64 - 2 * brow; ++brow; }
  int bcol = 2 * brow + rem;

  int t = threadIdx.x;
  int lane = t & 63, wv = t >> 6;
  int wr = wv >> 1, wc = wv & 1;   // 2 x 2 wave grid; per-wave C: 128x64
  int l15 = lane & 15;
  int ksel = ((lane >> 4) ^ ((lane >> 1) & 3)) * 8;

  int srow = t >> 2;                   // 0..63
  int scol = ((t & 3) ^ ((t >> 3) & 3)) * 8;
  const short* gA[4];
#pragma unroll
  for (int j = 0; j < 4; j++)
    gA[j] = Y + (size_t)(brow * 256 + j * 64 + srow) * KK + scol;
  const short* gB[2];
#pragma unroll
  for (int j = 0; j < 2; j++)
    gB[j] = Y + (size_t)(bcol * 128 + j * 64 + srow) * KK + scol;

  f32x4 acc[8][4] = {};

#define STAGE(tt, b) do {                                                   \
    short* base_ = lds + (b) * 12288;                                       \
    async_load16(gA[0] + (size_t)(tt) * BKT, base_ + 0 * 2048 + wv * 512);  \
    async_load16(gA[1] + (size_t)(tt) * BKT, base_ + 1 * 2048 + wv * 512);  \
    async_load16(gA[2] + (size_t)(tt) * BKT, base_ + 2 * 2048 + wv * 512);  \
    async_load16(gA[3] + (size_t)(tt) * BKT, base_ + 3 * 2048 + wv * 512);  \
    async_load16(gB[0] + (size_t)(tt) * BKT, base_ + 8192 + wv * 512);      \
    async_load16(gB[1] + (size_t)(tt) * BKT, base_ + 10240 + wv * 512);     \
  } while (0)

  STAGE(0, 0);
  STAGE(1, 1);

  for (int tt = 0; tt < NT; ++tt) {
    if (tt < NT - 1) asm volatile("s_waitcnt vmcnt(6)" ::: "memory");
    else             asm volatile("s_waitcnt vmcnt(0)" ::: "memory");
    __builtin_amdgcn_s_barrier();
    __builtin_amdgcn_sched_barrier(0);
    if (tt + 2 < NT) {
      int b = tt + 2;
      STAGE(b, b % 3);
    }

    const short* bufp = lds + (tt % 3) * 12288;
    short8 a[8], b[4];
#pragma unroll
    for (int m = 0; m < 8; m++)
      a[m] = *reinterpret_cast<const short8*>(
          &bufp[(wr * 128 + m * 16 + l15) * 32 + ksel]);
#pragma unroll
    for (int n = 0; n < 4; n++)
      b[n] = *reinterpret_cast<const short8*>(
          &bufp[8192 + (wc * 64 + n * 16 + l15) * 32 + ksel]);
    __builtin_amdgcn_s_setprio(1);
#pragma unroll
    for (int m = 0; m < 8; m++)
#pragma unroll
      for (int n = 0; n < 4; n++)
        acc[m][n] = __builtin_amdgcn_mfma_f32_16x16x32_bf16(a[m], b[n], acc[m][n], 0, 0, 0);
    __builtin_amdgcn_s_setprio(0);
  }

  // ---- epilogue: LDS-transposed, 256-B contiguous float4 segments, all nt ----
  int rbase = (lane >> 4) * 4;
  int row0 = brow * 256 + wr * 128;
  int colb = bcol * 128 + wc * 64;

  float* tbw = reinterpret_cast<float*>(lds) + wv * 2112;
  __builtin_amdgcn_s_barrier();
  __builtin_amdgcn_sched_barrier(0);

#pragma unroll
  for (int m = 0; m < 8; m++) {
#pragma unroll
    for (int n = 0; n < 4; n++)
#pragma unroll
      for (int r = 0; r < 4; r++)
        tbw[(rbase + r) * 68 + n * 16 + l15] = acc[m][n][r];
#pragma unroll
    for (int dr = 0; dr < 4; dr++) {
      f32x4 vv = *reinterpret_cast<const f32x4*>(
          &tbw[(dr * 4 + (lane >> 4)) * 68 + l15 * 4]);
      __builtin_nontemporal_store(
          vv, reinterpret_cast<f32x4*>(
              &C[(size_t)(row0 + m * 16 + dr * 4 + (lane >> 4)) * NN + colb + l15 * 4]));
    }
  }

#pragma unroll
  for (int n = 0; n < 4; n++) {
#pragma unroll
    for (int m = 0; m < 8; m++)
#pragma unroll
      for (int r = 0; r < 4; r++)
        tbw[l15 * 132 + m * 16 + rbase + r] = acc[m][n][r];
#pragma unroll
    for (int dr = 0; dr < 4; dr++)
#pragma unroll
      for (int half = 0; half < 2; half++) {
        f32x4 vv = *reinterpret_cast<const f32x4*>(
            &tbw[(dr * 4 + (lane >> 4)) * 132 + half * 64 + l15 * 4]);
        __builtin_nontemporal_store(
            vv, reinterpret_cast<f32x4*>(
                &C[(size_t)(colb + n * 16 + dr * 4 + (lane >> 4)) * NN +
                   row0 + half * 64 + l15 * 4]));
      }
  }
#undef STAGE
}

// ---------------- launch ----------------

extern "C" void kernel_launch(void* const* d_in, const int* in_sizes, int n_in,
                              void* d_out, int out_size, void* d_ws, size_t ws_size,
                              hipStream_t stream) {
  const float* h = (const float*)d_in[0];
  const float* e = (const float*)d_in[1];
  const int* src = (const int*)d_in[2];
  const int* dst = (const int*)d_in[3];
  float* out = (float*)d_out;
  char* ws = (char*)d_ws;

  short* Y     = (short*)(ws);                    // 16 MB
  short* xbb   = (short*)(ws + 20971520);         // 4 MB
  short* xcb   = (short*)(ws + 25165824);         // 4 MB
  float* k1    = (float*)(ws + 29360128);         // 8 MB
  int* cursor  = (int*)(ws + 37748736);           // 32 KB
  int2* edges  = (int2*)(ws + 37781504);          // 8 MB (8192 * 128 * 8B)

  clear_k<<<32, 256, 0, stream>>>(cursor);
  scatter_edges<<<EE / 256, 256, 0, stream>>>(src, dst, e, cursor, edges);
  spmm1_k<<<2048, 256, 0, stream>>>(h, cursor, edges, k1, xbb, Y);
  spmm2_k<<<2048, 256, 0, stream>>>(xbb, h, k1, cursor, edges, xcb, Y);
  spmm3_k<<<2048, 256, 0, stream>>>(xcb, h, k1, cursor, edges, Y);

  gram_gemm<<<1056, 256, 0, stream>>>(Y, out);
}